// Round 2
// baseline (473.600 us; speedup 1.0000x reference)
//
#include <hip/hip_runtime.h>

#define LOG2E 1.4426950408889634f

__device__ __forceinline__ float sigmoidf_(float z) {
    return 1.0f / (1.0f + exp2f(-z * LOG2E));
}

// ---------------------------------------------------------------------------
// Kernel 1: reverb loop. One block per batch. fb[4][64][64] in LDS as [s][c].
// ---------------------------------------------------------------------------
__global__ __launch_bounds__(1024) void reverb_kernel(
    const float* __restrict__ x, const float* __restrict__ rw, const float* __restrict__ dl,
    const float* __restrict__ fbw, const float* __restrict__ fbb,
    const float* __restrict__ d1w, const float* __restrict__ d1b,
    const float* __restrict__ d2w, const float* __restrict__ d2b,
    float* __restrict__ ws_wet)
{
    __shared__ float fbs[4096 * 4];      // fb[s][c], 64 KB
    __shared__ float fe[66];             // fade with zero pad at 0 and 65
    __shared__ float wvs[9][4][4];       // [n=ky*3+kx][cin][cout]
    __shared__ float s_rw[16], s_dl[16];
    __shared__ float s_d1w[2][4], s_d1b[2], s_d2w[4][2], s_d2b[4], s_fbb[4];

    const int tid = threadIdx.x;
    const int b = blockIdx.x;

    if (tid < 66) {
        float f = 0.0f;
        if (tid >= 1 && tid <= 64) {
            int j = tid - 1;
            f = 1.0f;
            if (j < 4) f = 0.6f + (0.4f / 3.0f) * j;
            else if (j >= 60) f = 0.6f + (0.4f / 3.0f) * (63 - j);
        }
        fe[tid] = f;
    }
    if (tid >= 128 && tid < 128 + 36) {
        int t2 = tid - 128; int cp = t2 / 9, n = t2 % 9;
        for (int c = 0; c < 4; ++c)
            wvs[n][cp][c] = fbw[(c * 4 + cp) * 9 + n];
    }
    if (tid >= 192 && tid < 208) s_rw[tid - 192] = rw[tid - 192];
    if (tid >= 256 && tid < 272) s_dl[tid - 256] = dl[tid - 256];
    if (tid == 320) {
        for (int j = 0; j < 2; ++j) {
            s_d1b[j] = d1b[j];
            for (int c = 0; c < 4; ++c) s_d1w[j][c] = d1w[j * 4 + c];
        }
        for (int c = 0; c < 4; ++c) {
            s_d2b[c] = d2b[c];
            s_d2w[c][0] = d2w[c * 2]; s_d2w[c][1] = d2w[c * 2 + 1];
            s_fbb[c] = fbb[c];
        }
    }
    // fb = 0.1 * x
    for (int c = 0; c < 4; ++c)
        for (int rix = 0; rix < 4; ++rix) {
            int s = tid + rix * 1024;
            fbs[s * 4 + c] = 0.1f * x[((b * 4 + c) << 12) + s];
        }
    __syncthreads();

    const int y = tid >> 4;
    const int x0 = (tid & 15) << 2;   // 4 consecutive x pixels per thread

    float acc[4][4];
    #pragma unroll
    for (int p = 0; p < 4; ++p)
        #pragma unroll
        for (int c = 0; c < 4; ++c) acc[p][c] = 0.0f;

    float decay = 1.0f;
    for (int i = 0; i < 16; ++i) {
        const float d = s_dl[i];
        const int ys  = ((int)(3.0f * d)) & 63;
        const int xs  = ((int)(6.0f * d)) & 63;
        const int ys2 = ((int)(1.5f * d)) & 63;
        const int xs2 = ((int)(3.0f * d)) & 63;
        const float wgt = sigmoidf_(s_rw[i]) * decay * 3.0f;

        int colIdx[6]; float fx[6];
        #pragma unroll
        for (int q = 0; q < 6; ++q) {
            int xx = x0 - 1 + q;
            colIdx[q] = (xx - xs) & 63;
            fx[q] = fe[xx + 1];
        }

        float r[4][4];
        #pragma unroll
        for (int p = 0; p < 4; ++p)
            #pragma unroll
            for (int c = 0; c < 4; ++c) r[p][c] = s_fbb[c];

        // r = conv3x3(roll(fb)*fade), zero-padded via fe==0 outside image
        #pragma unroll
        for (int a = 0; a < 3; ++a) {
            int yy = y - 1 + a;
            float fy = fe[yy + 1];
            int rb = ((yy - ys) & 63) << 6;
            #pragma unroll
            for (int q = 0; q < 6; ++q) {
                float f = fy * fx[q];
                const float* vp = &fbs[(rb + colIdx[q]) * 4];
                float s0 = vp[0] * f, s1 = vp[1] * f, s2 = vp[2] * f, s3 = vp[3] * f;
                #pragma unroll
                for (int p = 0; p < 4; ++p) {
                    if (p <= q && p >= q - 2) {
                        int n = a * 3 + (q - p);
                        #pragma unroll
                        for (int c = 0; c < 4; ++c)
                            r[p][c] += wvs[n][0][c] * s0 + wvs[n][1][c] * s1
                                     + wvs[n][2][c] * s2 + wvs[n][3][c] * s3;
                    }
                }
            }
        }

        // damping MLP + accumulate wet + fb increment
        float fbadd[4][4];
        #pragma unroll
        for (int p = 0; p < 4; ++p) {
            float z0 = s_d1w[0][0] * r[p][0] + s_d1w[0][1] * r[p][1]
                     + s_d1w[0][2] * r[p][2] + s_d1w[0][3] * r[p][3] + s_d1b[0];
            float z1 = s_d1w[1][0] * r[p][0] + s_d1w[1][1] * r[p][1]
                     + s_d1w[1][2] * r[p][2] + s_d1w[1][3] * r[p][3] + s_d1b[1];
            float h0 = z0 * sigmoidf_(z0);
            float h1 = z1 * sigmoidf_(z1);
            #pragma unroll
            for (int c = 0; c < 4; ++c) {
                float dm = sigmoidf_(s_d2w[c][0] * h0 + s_d2w[c][1] * h1 + s_d2b[c]);
                float rv = r[p][c] * dm;
                acc[p][c] += rv * wgt;
                fbadd[p][c] = rv * 0.24f;
            }
        }
        __syncthreads();
        #pragma unroll
        for (int p = 0; p < 4; ++p) {
            int s = (y << 6) + x0 + p;
            #pragma unroll
            for (int c = 0; c < 4; ++c) fbs[s * 4 + c] += fbadd[p][c];
        }
        __syncthreads();
        if (i > 0) {
            float prev[4][4];
            int rb2 = ((y - ys2) & 63) << 6;
            float fy2 = fe[y + 1];
            #pragma unroll
            for (int p = 0; p < 4; ++p) {
                int xp = x0 + p;
                const float* vp = &fbs[(rb2 + ((xp - xs2) & 63)) * 4];
                float f = fy2 * fe[xp + 1];
                #pragma unroll
                for (int c = 0; c < 4; ++c) prev[p][c] = vp[c] * f;
            }
            __syncthreads();
            #pragma unroll
            for (int p = 0; p < 4; ++p) {
                int s = (y << 6) + x0 + p;
                #pragma unroll
                for (int c = 0; c < 4; ++c) fbs[s * 4 + c] += 0.08f * prev[p][c];
            }
            __syncthreads();
        }
        decay *= 0.8f;
    }

    // store wet as [b][s][c] float4
    #pragma unroll
    for (int p = 0; p < 4; ++p) {
        int s = (y << 6) + x0 + p;
        ((float4*)ws_wet)[(b << 12) + s] =
            make_float4(acc[p][0], acc[p][1], acc[p][2], acc[p][3]);
    }
}

// ---------------------------------------------------------------------------
// Kernel 2: attention (head_dim = 1). Grid: 4b x 4h x 16 q-chunks = 256 blocks.
// 512 threads: rows (tid&255), k-range halves (tid>>8).
// ---------------------------------------------------------------------------
__global__ __launch_bounds__(512) void attn_kernel(
    const float4* __restrict__ wet, const float* __restrict__ aiw,
    const float* __restrict__ aib, float* __restrict__ o_out)
{
    __shared__ float4 kvs4[2048];        // (k,v) pairs for 4096 positions
    __shared__ float redmx[8], redmn[8];
    __shared__ float2 part[512];

    const int tid = threadIdx.x;
    const int bid = blockIdx.x;
    const int b  = bid >> 6;
    const int h  = (bid >> 4) & 3;
    const int qc = bid & 15;

    float wq[4], wk[4], wv[4];
    #pragma unroll
    for (int c = 0; c < 4; ++c) {
        wq[c] = aiw[h * 4 + c];
        wk[c] = aiw[(4 + h) * 4 + c];
        wv[c] = aiw[(8 + h) * 4 + c];
    }
    const float bq = aib[h], bk = aib[4 + h], bv = aib[8 + h];

    float2* kvs = (float2*)kvs4;
    float lmax = -1e30f, lmin = 1e30f;
    for (int s = tid; s < 4096; s += 512) {
        float4 w4 = wet[(b << 12) + s];
        float k = wk[0] * w4.x + wk[1] * w4.y + wk[2] * w4.z + wk[3] * w4.w + bk;
        float v = wv[0] * w4.x + wv[1] * w4.y + wv[2] * w4.z + wv[3] * w4.w + bv;
        kvs[s] = make_float2(k, v);
        lmax = fmaxf(lmax, k); lmin = fminf(lmin, k);
    }
    #pragma unroll
    for (int off = 32; off > 0; off >>= 1) {
        lmax = fmaxf(lmax, __shfl_xor(lmax, off));
        lmin = fminf(lmin, __shfl_xor(lmin, off));
    }
    if ((tid & 63) == 0) { redmx[tid >> 6] = lmax; redmn[tid >> 6] = lmin; }
    __syncthreads();
    float kmax = redmx[0], kmin = redmn[0];
    #pragma unroll
    for (int w = 1; w < 8; ++w) { kmax = fmaxf(kmax, redmx[w]); kmin = fminf(kmin, redmn[w]); }

    const int row  = qc * 256 + (tid & 255);
    const int half = tid >> 8;
    float4 w4 = wet[(b << 12) + row];
    float q = wq[0] * w4.x + wq[1] * w4.y + wq[2] * w4.z + wq[3] * w4.w + bq;
    float m = (q >= 0.0f) ? q * kmax : q * kmin;
    float qL = q * LOG2E, mL = m * LOG2E;

    float den = 0.0f, num = 0.0f;
    int j0 = half * 1024;
    #pragma unroll 4
    for (int j = j0; j < j0 + 1024; ++j) {
        float4 t = kvs4[j];
        float e0 = exp2f(fmaf(qL, t.x, -mL));
        float e1 = exp2f(fmaf(qL, t.z, -mL));
        den += e0 + e1;
        num = fmaf(e0, t.y, fmaf(e1, t.w, num));
    }
    part[tid] = make_float2(den, num);
    __syncthreads();
    if (half == 0) {
        den += part[tid + 256].x;
        num += part[tid + 256].y;
        o_out[((b << 12) + row) * 4 + h] = num / den;
    }
}

// ---------------------------------------------------------------------------
// Kernel 3: attention output projection -> wet2 planar [b][c][64*64]
// ---------------------------------------------------------------------------
__global__ __launch_bounds__(256) void proj_kernel(
    const float* __restrict__ o_in, const float* __restrict__ aow,
    const float* __restrict__ aob, float* __restrict__ wet2)
{
    int t = blockIdx.x * 256 + threadIdx.x;   // 16384
    int b = t >> 12, s = t & 4095;
    float4 o4 = ((const float4*)o_in)[t];
    #pragma unroll
    for (int c = 0; c < 4; ++c) {
        float val = aow[c * 4 + 0] * o4.x + aow[c * 4 + 1] * o4.y
                  + aow[c * 4 + 2] * o4.z + aow[c * 4 + 3] * o4.w
                  + aob[c];
        wet2[((b * 4 + c) << 12) + s] = val;
    }
}

// ---------------------------------------------------------------------------
// Kernel 4: depthwise 3x3 box blur (zero pad), /9
// ---------------------------------------------------------------------------
__global__ __launch_bounds__(256) void blur_kernel(
    const float* __restrict__ wet2, float* __restrict__ blur)
{
    int t = blockIdx.x * 256 + threadIdx.x;   // 16384
    int b = t >> 12, s = t & 4095;
    int y = s >> 6, x = s & 63;
    #pragma unroll
    for (int c = 0; c < 4; ++c) {
        const float* pl = wet2 + (((b * 4 + c)) << 12);
        float acc = 0.0f;
        for (int dy = -1; dy <= 1; ++dy) {
            int yy = y + dy;
            if (yy < 0 || yy > 63) continue;
            for (int dx = -1; dx <= 1; ++dx) {
                int xx = x + dx;
                if (xx < 0 || xx > 63) continue;
                acc += pl[yy * 64 + xx];
            }
        }
        blur[((b * 4 + c) << 12) + s] = acc * (1.0f / 9.0f);
    }
}

// ---------------------------------------------------------------------------
// Kernel 5: edge enhance + spatial conv + 1x1 combine + dry/wet mix
// ---------------------------------------------------------------------------
__global__ __launch_bounds__(256) void final_kernel(
    const float* __restrict__ x, const float* __restrict__ sw, const float* __restrict__ sb,
    const float* __restrict__ ow, const float* __restrict__ ob,
    const float* __restrict__ blur, float* __restrict__ out)
{
    __shared__ float s_sw[288], s_ow[48], s_sb[8], s_ob[4];
    int tid = threadIdx.x;
    for (int j = tid; j < 288; j += 256) s_sw[j] = sw[j];
    if (tid < 48) s_ow[tid] = ow[tid];
    if (tid < 8) s_sb[tid] = sb[tid];
    if (tid < 4) s_ob[tid] = ob[tid];
    __syncthreads();

    int t = blockIdx.x * 256 + tid;   // 16384
    int b = t >> 12, s = t & 4095;
    int y = s >> 6, xx0 = s & 63;

    // spatial_features = conv3x3(x, spatial_w) + spatial_b  (8 out ch)
    float spat[8];
    #pragma unroll
    for (int co = 0; co < 8; ++co) spat[co] = s_sb[co];
    for (int dy = -1; dy <= 1; ++dy) {
        int yy = y + dy;
        if (yy < 0 || yy > 63) continue;
        for (int dx = -1; dx <= 1; ++dx) {
            int xc = xx0 + dx;
            if (xc < 0 || xc > 63) continue;
            int ky = dy + 1, kx = dx + 1;
            #pragma unroll
            for (int ci = 0; ci < 4; ++ci) {
                float xv = x[((b * 4 + ci) << 12) + yy * 64 + xc];
                #pragma unroll
                for (int co = 0; co < 8; ++co)
                    spat[co] += s_sw[((co * 4 + ci) * 3 + ky) * 3 + kx] * xv;
            }
        }
    }

    // wetF = blur + 0.04 * edge,  edge = 9*blur_center - boxsum3(blur)
    float wetF[4];
    #pragma unroll
    for (int c = 0; c < 4; ++c) {
        const float* pl = blur + ((b * 4 + c) << 12);
        float center = pl[s];
        float sum9 = 0.0f;
        for (int dy = -1; dy <= 1; ++dy) {
            int yy = y + dy;
            if (yy < 0 || yy > 63) continue;
            for (int dx = -1; dx <= 1; ++dx) {
                int xc = xx0 + dx;
                if (xc < 0 || xc > 63) continue;
                sum9 += pl[yy * 64 + xc];
            }
        }
        float edge = 9.0f * center - sum9;
        wetF[c] = center + 0.04f * edge;
    }

    #pragma unroll
    for (int co = 0; co < 4; ++co) {
        float p = s_ob[co];
        #pragma unroll
        for (int j = 0; j < 8; ++j) p += s_ow[co * 12 + j] * spat[j];
        #pragma unroll
        for (int c = 0; c < 4; ++c) p += s_ow[co * 12 + 8 + c] * wetF[c];
        float xc = x[((b * 4 + co) << 12) + s];
        out[((b * 4 + co) << 12) + s] = 0.7f * xc + 0.3f * p;
    }
}

// ---------------------------------------------------------------------------
extern "C" void kernel_launch(void* const* d_in, const int* in_sizes, int n_in,
                              void* d_out, int out_size, void* d_ws, size_t ws_size,
                              hipStream_t stream)
{
    (void)in_sizes; (void)n_in; (void)out_size; (void)ws_size;
    const float* x    = (const float*)d_in[0];
    const float* rw   = (const float*)d_in[1];
    const float* dl   = (const float*)d_in[2];
    // d_in[3] diffusion_strength: unused by reference
    const float* sw   = (const float*)d_in[4];
    const float* sb   = (const float*)d_in[5];
    const float* fbw  = (const float*)d_in[6];
    const float* fbb  = (const float*)d_in[7];
    const float* d1w  = (const float*)d_in[8];
    const float* d1b  = (const float*)d_in[9];
    const float* d2w  = (const float*)d_in[10];
    const float* d2b  = (const float*)d_in[11];
    const float* aiw  = (const float*)d_in[12];
    const float* aib  = (const float*)d_in[13];
    const float* aow  = (const float*)d_in[14];
    const float* aob  = (const float*)d_in[15];
    const float* ow   = (const float*)d_in[16];
    const float* ob   = (const float*)d_in[17];
    float* out = (float*)d_out;

    float* ws_wet  = (float*)d_ws;           // [4][4096][4]
    float* ws_o    = ws_wet + 65536;         // [4][4096][4]
    float* ws_wet2 = ws_o + 65536;           // [4][4][4096]
    float* ws_blur = ws_wet2 + 65536;        // [4][4][4096]

    reverb_kernel<<<4, 1024, 0, stream>>>(x, rw, dl, fbw, fbb, d1w, d1b, d2w, d2b, ws_wet);
    attn_kernel<<<256, 512, 0, stream>>>((const float4*)ws_wet, aiw, aib, ws_o);
    proj_kernel<<<64, 256, 0, stream>>>(ws_o, aow, aob, ws_wet2);
    blur_kernel<<<64, 256, 0, stream>>>(ws_wet2, ws_blur);
    final_kernel<<<64, 256, 0, stream>>>(x, sw, sb, ow, ob, ws_blur, out);
}

// Round 3
// 352.438 us; speedup vs baseline: 1.3438x; 1.3438x over previous
//
#include <hip/hip_runtime.h>

#define LOG2E 1.4426950408889634f

// fast sigmoid: rcp approx is ~1e-6 rel; tolerance headroom is huge
__device__ __forceinline__ float fsig(float z) {
    return __builtin_amdgcn_rcpf(1.0f + exp2f(-z * LOG2E));
}

// ---------------------------------------------------------------------------
// Reverb iteration core: conv3x3(roll(fb)*fade) + damping MLP.
// Weights read as float4 (1 ds_read_b128 per 16 FMA); fb snapshot read as
// float4 (b128, 2-way bank aliasing = free). fb/acc live in registers.
// ---------------------------------------------------------------------------
__device__ __forceinline__ void conv_mlp(
    const float4* src, int y, int x0, int ys, int xs, float wgt,
    const float* fe, const float4* wvs4,
    const float4* s_d1w4, const float* s_d1b2, const float4* s_d2p,
    float fbv[4][4], float acc[4][4])
{
    int colIdx[6]; float fx[6];
    #pragma unroll
    for (int q = 0; q < 6; ++q) {
        int xx = x0 - 1 + q;
        colIdx[q] = (xx - xs) & 63;
        fx[q] = fe[xx + 1];
    }
    float r[4][4];
    #pragma unroll
    for (int c = 0; c < 4; ++c) {
        float fb_b = s_d2p[c].w;     // conv bias (fbb) packed in .w
        #pragma unroll
        for (int p = 0; p < 4; ++p) r[p][c] = fb_b;
    }
    #pragma unroll
    for (int a = 0; a < 3; ++a) {
        int yy = y - 1 + a;
        float fy = fe[yy + 1];
        int rb = ((yy - ys) & 63) << 6;
        float4 colv[6];
        #pragma unroll
        for (int q = 0; q < 6; ++q) {
            float4 v = src[rb + colIdx[q]];
            float f = fy * fx[q];
            colv[q] = make_float4(v.x * f, v.y * f, v.z * f, v.w * f);
        }
        #pragma unroll
        for (int n0 = 0; n0 < 3; ++n0) {
            #pragma unroll
            for (int co = 0; co < 4; ++co) {
                float4 wv = wvs4[(a * 3 + n0) * 4 + co];
                #pragma unroll
                for (int p = 0; p < 4; ++p) {
                    float4 cv = colv[p + n0];
                    r[p][co] = fmaf(wv.x, cv.x, fmaf(wv.y, cv.y,
                               fmaf(wv.z, cv.z, fmaf(wv.w, cv.w, r[p][co]))));
                }
            }
        }
    }
    float4 W0 = s_d1w4[0], W1 = s_d1w4[1];
    float B0 = s_d1b2[0], B1 = s_d1b2[1];
    #pragma unroll
    for (int p = 0; p < 4; ++p) {
        float z0 = fmaf(W0.x, r[p][0], fmaf(W0.y, r[p][1],
                   fmaf(W0.z, r[p][2], fmaf(W0.w, r[p][3], B0))));
        float z1 = fmaf(W1.x, r[p][0], fmaf(W1.y, r[p][1],
                   fmaf(W1.z, r[p][2], fmaf(W1.w, r[p][3], B1))));
        float h0 = z0 * fsig(z0);
        float h1 = z1 * fsig(z1);
        #pragma unroll
        for (int c = 0; c < 4; ++c) {
            float4 dp = s_d2p[c];
            float dm = fsig(fmaf(dp.x, h0, fmaf(dp.y, h1, dp.z)));
            float rv = r[p][c] * dm;
            acc[p][c] = fmaf(rv, wgt, acc[p][c]);
            fbv[p][c] = fmaf(rv, 0.24f, fbv[p][c]);
        }
    }
}

// ---------------------------------------------------------------------------
// Kernel 1: reverb loop. One block per batch; fb snapshot double-buffered in
// LDS (bufA/bufB, fixed roles), fb itself register-resident. 2 barriers/iter.
// ---------------------------------------------------------------------------
__global__ __launch_bounds__(1024) void reverb_kernel(
    const float* __restrict__ x, const float* __restrict__ rw, const float* __restrict__ dl,
    const float* __restrict__ fbw, const float* __restrict__ fbb,
    const float* __restrict__ d1w, const float* __restrict__ d1b,
    const float* __restrict__ d2w, const float* __restrict__ d2b,
    float* __restrict__ ws_wet)
{
    __shared__ float4 bufA[4096];    // 64 KB
    __shared__ float4 bufB[4096];    // 64 KB
    __shared__ float fe[66];         // fade, zero pad at 0 and 65
    __shared__ float4 wvs4[36];      // [n=ky*3+kx][cout] -> (cin0..3)
    __shared__ float s_rw[16], s_dl[16];
    __shared__ float4 s_d1w4[2];
    __shared__ float s_d1b2[2];
    __shared__ float4 s_d2p[4];      // (d2w0, d2w1, d2b, fbb)

    const int tid = threadIdx.x;
    const int b = blockIdx.x;

    if (tid < 66) {
        float f = 0.0f;
        if (tid >= 1 && tid <= 64) {
            int j = tid - 1;
            f = 1.0f;
            if (j < 4) f = 0.6f + (0.4f / 3.0f) * j;
            else if (j >= 60) f = 0.6f + (0.4f / 3.0f) * (63 - j);
        }
        fe[tid] = f;
    }
    if (tid >= 128 && tid < 164) {
        int t2 = tid - 128, n = t2 >> 2, co = t2 & 3;
        wvs4[t2] = make_float4(fbw[(co * 4 + 0) * 9 + n], fbw[(co * 4 + 1) * 9 + n],
                               fbw[(co * 4 + 2) * 9 + n], fbw[(co * 4 + 3) * 9 + n]);
    }
    if (tid >= 192 && tid < 208) s_rw[tid - 192] = rw[tid - 192];
    if (tid >= 256 && tid < 272) s_dl[tid - 256] = dl[tid - 256];
    if (tid == 320) {
        for (int j = 0; j < 2; ++j) {
            s_d1w4[j] = make_float4(d1w[j * 4], d1w[j * 4 + 1], d1w[j * 4 + 2], d1w[j * 4 + 3]);
            s_d1b2[j] = d1b[j];
        }
        for (int c = 0; c < 4; ++c)
            s_d2p[c] = make_float4(d2w[c * 2], d2w[c * 2 + 1], d2b[c], fbb[c]);
    }

    const int y = tid >> 4;
    const int x0 = (tid & 15) << 2;

    float fbv[4][4], acc[4][4];
    #pragma unroll
    for (int p = 0; p < 4; ++p) {
        int s = (y << 6) + x0 + p;
        #pragma unroll
        for (int c = 0; c < 4; ++c) {
            fbv[p][c] = 0.1f * x[((b * 4 + c) << 12) + s];
            acc[p][c] = 0.0f;
        }
        bufA[s] = make_float4(fbv[p][0], fbv[p][1], fbv[p][2], fbv[p][3]);
    }
    __syncthreads();

    // i = 0: conv reads bufA, no prev phase, snapshot -> bufB
    {
        float d = s_dl[0];
        int ys = ((int)(3.0f * d)) & 63, xs = ((int)(6.0f * d)) & 63;
        float wgt = fsig(s_rw[0]) * 3.0f;
        conv_mlp(bufA, y, x0, ys, xs, wgt, fe, wvs4, s_d1w4, s_d1b2, s_d2p, fbv, acc);
        #pragma unroll
        for (int p = 0; p < 4; ++p) {
            int s = (y << 6) + x0 + p;
            bufB[s] = make_float4(fbv[p][0], fbv[p][1], fbv[p][2], fbv[p][3]);
        }
        __syncthreads();
    }

    float decay = 0.8f;
    for (int i = 1; i < 16; ++i) {
        float d = s_dl[i];
        int ys  = ((int)(3.0f * d)) & 63;
        int xs  = ((int)(6.0f * d)) & 63;
        int ys2 = ((int)(1.5f * d)) & 63;
        int xs2 = ((int)(3.0f * d)) & 63;
        float wgt = fsig(s_rw[i]) * decay * 3.0f;

        // conv reads bufB (current snapshot)
        conv_mlp(bufB, y, x0, ys, xs, wgt, fe, wvs4, s_d1w4, s_d1b2, s_d2p, fbv, acc);

        // intermediate snapshot (after 0.24 update) -> bufA
        #pragma unroll
        for (int p = 0; p < 4; ++p) {
            int s = (y << 6) + x0 + p;
            bufA[s] = make_float4(fbv[p][0], fbv[p][1], fbv[p][2], fbv[p][3]);
        }
        __syncthreads();

        // prev = roll(fb_inter) * fades, fb += 0.08*prev
        {
            int rb2 = ((y - ys2) & 63) << 6;
            float fy2 = fe[y + 1];
            #pragma unroll
            for (int p = 0; p < 4; ++p) {
                int xp = x0 + p;
                float4 v = bufA[rb2 + ((xp - xs2) & 63)];
                float f = 0.08f * fy2 * fe[xp + 1];
                fbv[p][0] = fmaf(v.x, f, fbv[p][0]);
                fbv[p][1] = fmaf(v.y, f, fbv[p][1]);
                fbv[p][2] = fmaf(v.z, f, fbv[p][2]);
                fbv[p][3] = fmaf(v.w, f, fbv[p][3]);
            }
        }
        // final snapshot -> bufB (safe: all conv reads of bufB passed mid-sync)
        #pragma unroll
        for (int p = 0; p < 4; ++p) {
            int s = (y << 6) + x0 + p;
            bufB[s] = make_float4(fbv[p][0], fbv[p][1], fbv[p][2], fbv[p][3]);
        }
        __syncthreads();
        decay *= 0.8f;
    }

    #pragma unroll
    for (int p = 0; p < 4; ++p) {
        int s = (y << 6) + x0 + p;
        ((float4*)ws_wet)[(b << 12) + s] =
            make_float4(acc[p][0], acc[p][1], acc[p][2], acc[p][3]);
    }
}

// ---------------------------------------------------------------------------
// Kernel 2: attention (head_dim=1). Grid: 4b x 4h x 32 q-chunks = 512 blocks,
// 512 threads: 128 rows x 4 key-quarters. 2 blocks/CU.
// ---------------------------------------------------------------------------
__global__ __launch_bounds__(512) void attn_kernel(
    const float4* __restrict__ wet, const float* __restrict__ aiw,
    const float* __restrict__ aib, float* __restrict__ o_out)
{
    __shared__ float4 kvs4[2048];        // (k,v) pairs for 4096 positions
    __shared__ float redmx[8], redmn[8];
    __shared__ float2 part[512];

    const int tid = threadIdx.x;
    const int bid = blockIdx.x;
    const int b  = bid >> 7;
    const int h  = (bid >> 5) & 3;
    const int qc = bid & 31;

    float wq[4], wk[4], wv[4];
    #pragma unroll
    for (int c = 0; c < 4; ++c) {
        wq[c] = aiw[h * 4 + c];
        wk[c] = aiw[(4 + h) * 4 + c];
        wv[c] = aiw[(8 + h) * 4 + c];
    }
    const float bq = aib[h], bk = aib[4 + h], bv = aib[8 + h];

    float2* kvs = (float2*)kvs4;
    float lmax = -1e30f, lmin = 1e30f;
    for (int s = tid; s < 4096; s += 512) {
        float4 w4 = wet[(b << 12) + s];
        float k = wk[0] * w4.x + wk[1] * w4.y + wk[2] * w4.z + wk[3] * w4.w + bk;
        float v = wv[0] * w4.x + wv[1] * w4.y + wv[2] * w4.z + wv[3] * w4.w + bv;
        kvs[s] = make_float2(k, v);
        lmax = fmaxf(lmax, k); lmin = fminf(lmin, k);
    }
    #pragma unroll
    for (int off = 32; off > 0; off >>= 1) {
        lmax = fmaxf(lmax, __shfl_xor(lmax, off));
        lmin = fminf(lmin, __shfl_xor(lmin, off));
    }
    if ((tid & 63) == 0) { redmx[tid >> 6] = lmax; redmn[tid >> 6] = lmin; }
    __syncthreads();
    float kmax = redmx[0], kmin = redmn[0];
    #pragma unroll
    for (int w = 1; w < 8; ++w) { kmax = fmaxf(kmax, redmx[w]); kmin = fminf(kmin, redmn[w]); }

    const int rloc = tid & 127;
    const int quarter = tid >> 7;
    const int row = qc * 128 + rloc;
    float4 w4 = wet[(b << 12) + row];
    float q = wq[0] * w4.x + wq[1] * w4.y + wq[2] * w4.z + wq[3] * w4.w + bq;
    float m = (q >= 0.0f) ? q * kmax : q * kmin;   // exact row max (hd=1)
    float qL = q * LOG2E, mL = m * LOG2E;

    float den0 = 0.0f, den1 = 0.0f, num0 = 0.0f, num1 = 0.0f;
    int j0 = quarter * 512;
    #pragma unroll 2
    for (int j = j0; j < j0 + 512; j += 2) {
        float4 t0 = kvs4[j], t1 = kvs4[j + 1];
        float e0 = exp2f(fmaf(qL, t0.x, -mL));
        float e1 = exp2f(fmaf(qL, t0.z, -mL));
        float e2 = exp2f(fmaf(qL, t1.x, -mL));
        float e3 = exp2f(fmaf(qL, t1.z, -mL));
        den0 += e0 + e1; den1 += e2 + e3;
        num0 = fmaf(e0, t0.y, fmaf(e1, t0.w, num0));
        num1 = fmaf(e2, t1.y, fmaf(e3, t1.w, num1));
    }
    part[tid] = make_float2(den0 + den1, num0 + num1);
    __syncthreads();
    if (quarter == 0) {
        float den = part[tid].x + part[tid + 128].x + part[tid + 256].x + part[tid + 384].x;
        float num = part[tid].y + part[tid + 128].y + part[tid + 256].y + part[tid + 384].y;
        o_out[((b << 12) + row) * 4 + h] = num * __builtin_amdgcn_rcpf(den);
    }
}

// ---------------------------------------------------------------------------
// Kernel 3: fused attn output projection + depthwise 3x3 box blur.
// One block per (batch, channel) plane; wet2 plane lives in LDS only.
// ---------------------------------------------------------------------------
__global__ __launch_bounds__(256) void projblur_kernel(
    const float4* __restrict__ o_in, const float* __restrict__ aow,
    const float* __restrict__ aob, float* __restrict__ blur)
{
    __shared__ float wetL[4096];
    const int tid = threadIdx.x;
    const int bc = blockIdx.x;          // b*4 + c
    const int b = bc >> 2, c = bc & 3;
    const float w0 = aow[c * 4], w1 = aow[c * 4 + 1], w2 = aow[c * 4 + 2], w3 = aow[c * 4 + 3];
    const float bb = aob[c];
    for (int s = tid; s < 4096; s += 256) {
        float4 o = o_in[(b << 12) + s];
        wetL[s] = w0 * o.x + w1 * o.y + w2 * o.z + w3 * o.w + bb;
    }
    __syncthreads();
    for (int s = tid; s < 4096; s += 256) {
        int y = s >> 6, x = s & 63;
        float acc = 0.0f;
        for (int dy = -1; dy <= 1; ++dy) {
            int yy = y + dy; if (yy < 0 || yy > 63) continue;
            for (int dx = -1; dx <= 1; ++dx) {
                int xx = x + dx; if (xx < 0 || xx > 63) continue;
                acc += wetL[yy * 64 + xx];
            }
        }
        blur[(bc << 12) + s] = acc * (1.0f / 9.0f);
    }
}

// ---------------------------------------------------------------------------
// Kernel 4: edge enhance + spatial conv + 1x1 combine + dry/wet mix
// ---------------------------------------------------------------------------
__global__ __launch_bounds__(256) void final_kernel(
    const float* __restrict__ x, const float* __restrict__ sw, const float* __restrict__ sb,
    const float* __restrict__ ow, const float* __restrict__ ob,
    const float* __restrict__ blur, float* __restrict__ out)
{
    __shared__ float s_sw[288], s_ow[48], s_sb[8], s_ob[4];
    int tid = threadIdx.x;
    for (int j = tid; j < 288; j += 256) s_sw[j] = sw[j];
    if (tid < 48) s_ow[tid] = ow[tid];
    if (tid < 8) s_sb[tid] = sb[tid];
    if (tid < 4) s_ob[tid] = ob[tid];
    __syncthreads();

    int t = blockIdx.x * 256 + tid;   // 16384
    int b = t >> 12, s = t & 4095;
    int y = s >> 6, xx0 = s & 63;

    float spat[8];
    #pragma unroll
    for (int co = 0; co < 8; ++co) spat[co] = s_sb[co];
    for (int dy = -1; dy <= 1; ++dy) {
        int yy = y + dy;
        if (yy < 0 || yy > 63) continue;
        for (int dx = -1; dx <= 1; ++dx) {
            int xc = xx0 + dx;
            if (xc < 0 || xc > 63) continue;
            int ky = dy + 1, kx = dx + 1;
            #pragma unroll
            for (int ci = 0; ci < 4; ++ci) {
                float xv = x[((b * 4 + ci) << 12) + yy * 64 + xc];
                #pragma unroll
                for (int co = 0; co < 8; ++co)
                    spat[co] += s_sw[((co * 4 + ci) * 3 + ky) * 3 + kx] * xv;
            }
        }
    }

    float wetF[4];
    #pragma unroll
    for (int c = 0; c < 4; ++c) {
        const float* pl = blur + ((b * 4 + c) << 12);
        float center = pl[s];
        float sum9 = 0.0f;
        for (int dy = -1; dy <= 1; ++dy) {
            int yy = y + dy;
            if (yy < 0 || yy > 63) continue;
            for (int dx = -1; dx <= 1; ++dx) {
                int xc = xx0 + dx;
                if (xc < 0 || xc > 63) continue;
                sum9 += pl[yy * 64 + xc];
            }
        }
        float edge = 9.0f * center - sum9;
        wetF[c] = center + 0.04f * edge;
    }

    #pragma unroll
    for (int co = 0; co < 4; ++co) {
        float p = s_ob[co];
        #pragma unroll
        for (int j = 0; j < 8; ++j) p += s_ow[co * 12 + j] * spat[j];
        #pragma unroll
        for (int c = 0; c < 4; ++c) p += s_ow[co * 12 + 8 + c] * wetF[c];
        float xc = x[((b * 4 + co) << 12) + s];
        out[((b * 4 + co) << 12) + s] = 0.7f * xc + 0.3f * p;
    }
}

// ---------------------------------------------------------------------------
extern "C" void kernel_launch(void* const* d_in, const int* in_sizes, int n_in,
                              void* d_out, int out_size, void* d_ws, size_t ws_size,
                              hipStream_t stream)
{
    (void)in_sizes; (void)n_in; (void)out_size; (void)ws_size;
    const float* x    = (const float*)d_in[0];
    const float* rw   = (const float*)d_in[1];
    const float* dl   = (const float*)d_in[2];
    // d_in[3] diffusion_strength: unused by reference
    const float* sw   = (const float*)d_in[4];
    const float* sb   = (const float*)d_in[5];
    const float* fbw  = (const float*)d_in[6];
    const float* fbb  = (const float*)d_in[7];
    const float* d1w  = (const float*)d_in[8];
    const float* d1b  = (const float*)d_in[9];
    const float* d2w  = (const float*)d_in[10];
    const float* d2b  = (const float*)d_in[11];
    const float* aiw  = (const float*)d_in[12];
    const float* aib  = (const float*)d_in[13];
    const float* aow  = (const float*)d_in[14];
    const float* aob  = (const float*)d_in[15];
    const float* ow   = (const float*)d_in[16];
    const float* ob   = (const float*)d_in[17];
    float* out = (float*)d_out;

    float* ws_wet  = (float*)d_ws;           // [4][4096][4]
    float* ws_o    = ws_wet + 65536;         // [4][4096][4]
    float* ws_blur = ws_o + 65536;           // [4][4][4096]

    reverb_kernel<<<4, 1024, 0, stream>>>(x, rw, dl, fbw, fbb, d1w, d1b, d2w, d2b, ws_wet);
    attn_kernel<<<512, 512, 0, stream>>>((const float4*)ws_wet, aiw, aib, ws_o);
    projblur_kernel<<<16, 256, 0, stream>>>((const float4*)ws_o, aow, aob, ws_blur);
    final_kernel<<<64, 256, 0, stream>>>(x, sw, sb, ow, ob, ws_blur, out);
}

// Round 4
// 301.807 us; speedup vs baseline: 1.5692x; 1.1678x over previous
//
#include <hip/hip_runtime.h>

#define LOG2E 1.4426950408889634f

typedef float v2f __attribute__((ext_vector_type(2)));

__device__ __forceinline__ v2f pk_fma(v2f a, v2f b, v2f c) {
    return __builtin_elementwise_fma(a, b, c);
}

// fast sigmoid: rcp approx is ~1e-6 rel; tolerance headroom is huge
__device__ __forceinline__ float fsig(float z) {
    return __builtin_amdgcn_rcpf(1.0f + exp2f(-z * LOG2E));
}

// within-row 4x16 transpose: kills the stride-4 8-way bank aliasing
__device__ __forceinline__ int permc(int col) {
    return ((col & 3) << 4) | (col >> 2);
}

// ---------------------------------------------------------------------------
// Reverb iteration core: conv3x3(roll(fb)*fade) + damping MLP.
// LDS layout is row-major with permc() column swizzle; all accesses are
// float4 at consecutive slots across lanes -> structural-minimum conflicts.
// Conv inner product in packed fp32 (v_pk_fma_f32).
// ---------------------------------------------------------------------------
__device__ __forceinline__ void conv_mlp(
    const float4* src, int y, int x0, int ys, int xs, float wgt,
    const float* fe, const float4* wvs4,
    const float4* s_d1w4, const float* s_d1b2, const float4* s_d2p,
    float fbv[4][4], float acc[4][4])
{
    int pcol[6]; float fx[6];
    #pragma unroll
    for (int q = 0; q < 6; ++q) {
        int xx = x0 - 1 + q;
        int cc = (xx - xs) & 63;
        pcol[q] = permc(cc);
        fx[q] = fe[xx + 1];
    }
    v2f r2[4][4];
    #pragma unroll
    for (int p = 0; p < 4; ++p)
        #pragma unroll
        for (int c = 0; c < 4; ++c) r2[p][c] = (v2f){0.0f, 0.0f};

    #pragma unroll
    for (int a = 0; a < 3; ++a) {
        int yy = y - 1 + a;
        float fy = fe[yy + 1];
        int rb = ((yy - ys) & 63) << 6;
        v2f cl[6], ch[6];
        #pragma unroll
        for (int q = 0; q < 6; ++q) {
            float4 v = src[rb + pcol[q]];
            v2f f2 = (v2f){fy * fx[q], fy * fx[q]};
            cl[q] = (v2f){v.x, v.y} * f2;
            ch[q] = (v2f){v.z, v.w} * f2;
        }
        #pragma unroll
        for (int n0 = 0; n0 < 3; ++n0) {
            #pragma unroll
            for (int co = 0; co < 4; ++co) {
                float4 wv = wvs4[(a * 3 + n0) * 4 + co];
                v2f wlo = (v2f){wv.x, wv.y}, whi = (v2f){wv.z, wv.w};
                #pragma unroll
                for (int p = 0; p < 4; ++p)
                    r2[p][co] = pk_fma(wlo, cl[p + n0], pk_fma(whi, ch[p + n0], r2[p][co]));
            }
        }
    }
    float r[4][4];
    #pragma unroll
    for (int p = 0; p < 4; ++p)
        #pragma unroll
        for (int c = 0; c < 4; ++c)
            r[p][c] = r2[p][c].x + r2[p][c].y + s_d2p[c].w;   // + conv bias (fbb)

    float4 W0 = s_d1w4[0], W1 = s_d1w4[1];
    float B0 = s_d1b2[0], B1 = s_d1b2[1];
    #pragma unroll
    for (int p = 0; p < 4; ++p) {
        float z0 = fmaf(W0.x, r[p][0], fmaf(W0.y, r[p][1],
                   fmaf(W0.z, r[p][2], fmaf(W0.w, r[p][3], B0))));
        float z1 = fmaf(W1.x, r[p][0], fmaf(W1.y, r[p][1],
                   fmaf(W1.z, r[p][2], fmaf(W1.w, r[p][3], B1))));
        float h0 = z0 * fsig(z0);
        float h1 = z1 * fsig(z1);
        #pragma unroll
        for (int c = 0; c < 4; ++c) {
            float4 dp = s_d2p[c];
            float dm = fsig(fmaf(dp.x, h0, fmaf(dp.y, h1, dp.z)));
            float rv = r[p][c] * dm;
            acc[p][c] = fmaf(rv, wgt, acc[p][c]);
            fbv[p][c] = fmaf(rv, 0.24f, fbv[p][c]);
        }
    }
}

// ---------------------------------------------------------------------------
// Kernel 1: reverb loop. One block per batch; fb snapshot double-buffered in
// LDS (bufA/bufB, swizzled layout), fb itself register-resident.
// ---------------------------------------------------------------------------
__global__ __launch_bounds__(1024) void reverb_kernel(
    const float* __restrict__ x, const float* __restrict__ rw, const float* __restrict__ dl,
    const float* __restrict__ fbw, const float* __restrict__ fbb,
    const float* __restrict__ d1w, const float* __restrict__ d1b,
    const float* __restrict__ d2w, const float* __restrict__ d2b,
    float* __restrict__ ws_wet)
{
    __shared__ float4 bufA[4096];    // 64 KB, [row][permc(col)]
    __shared__ float4 bufB[4096];    // 64 KB
    __shared__ float fe[66];         // fade, zero pad at 0 and 65
    __shared__ float4 wvs4[36];      // [n=ky*3+kx][cout] -> (cin0..3)
    __shared__ float s_rw[16], s_dl[16];
    __shared__ float4 s_d1w4[2];
    __shared__ float s_d1b2[2];
    __shared__ float4 s_d2p[4];      // (d2w0, d2w1, d2b, fbb)

    const int tid = threadIdx.x;
    const int b = blockIdx.x;

    if (tid < 66) {
        float f = 0.0f;
        if (tid >= 1 && tid <= 64) {
            int j = tid - 1;
            f = 1.0f;
            if (j < 4) f = 0.6f + (0.4f / 3.0f) * j;
            else if (j >= 60) f = 0.6f + (0.4f / 3.0f) * (63 - j);
        }
        fe[tid] = f;
    }
    if (tid >= 128 && tid < 164) {
        int t2 = tid - 128, n = t2 >> 2, co = t2 & 3;
        wvs4[t2] = make_float4(fbw[(co * 4 + 0) * 9 + n], fbw[(co * 4 + 1) * 9 + n],
                               fbw[(co * 4 + 2) * 9 + n], fbw[(co * 4 + 3) * 9 + n]);
    }
    if (tid >= 192 && tid < 208) s_rw[tid - 192] = rw[tid - 192];
    if (tid >= 256 && tid < 272) s_dl[tid - 256] = dl[tid - 256];
    if (tid == 320) {
        for (int j = 0; j < 2; ++j) {
            s_d1w4[j] = make_float4(d1w[j * 4], d1w[j * 4 + 1], d1w[j * 4 + 2], d1w[j * 4 + 3]);
            s_d1b2[j] = d1b[j];
        }
        for (int c = 0; c < 4; ++c)
            s_d2p[c] = make_float4(d2w[c * 2], d2w[c * 2 + 1], d2b[c], fbb[c]);
    }

    const int y = tid >> 4;
    const int t = tid & 15;
    const int x0 = t << 2;
    // swizzled slot for pixel (y, x0+p): (y<<6) | (p<<4) | t
    const int wbase = (y << 6) | t;

    float fbv[4][4], acc[4][4];
    #pragma unroll
    for (int c = 0; c < 4; ++c) {
        float4 xv = ((const float4*)(x + ((b * 4 + c) << 12)))[(y << 4) | t];
        fbv[0][c] = 0.1f * xv.x; fbv[1][c] = 0.1f * xv.y;
        fbv[2][c] = 0.1f * xv.z; fbv[3][c] = 0.1f * xv.w;
        #pragma unroll
        for (int p = 0; p < 4; ++p) acc[p][c] = 0.0f;
    }
    #pragma unroll
    for (int p = 0; p < 4; ++p)
        bufA[wbase | (p << 4)] = make_float4(fbv[p][0], fbv[p][1], fbv[p][2], fbv[p][3]);
    __syncthreads();

    // i = 0: conv reads bufA, no prev phase, snapshot -> bufB
    {
        float d = s_dl[0];
        int ys = ((int)(3.0f * d)) & 63, xs = ((int)(6.0f * d)) & 63;
        float wgt = fsig(s_rw[0]) * 3.0f;
        conv_mlp(bufA, y, x0, ys, xs, wgt, fe, wvs4, s_d1w4, s_d1b2, s_d2p, fbv, acc);
        #pragma unroll
        for (int p = 0; p < 4; ++p)
            bufB[wbase | (p << 4)] = make_float4(fbv[p][0], fbv[p][1], fbv[p][2], fbv[p][3]);
        __syncthreads();
    }

    float decay = 0.8f;
    for (int i = 1; i < 16; ++i) {
        float d = s_dl[i];
        int ys  = ((int)(3.0f * d)) & 63;
        int xs  = ((int)(6.0f * d)) & 63;
        int ys2 = ((int)(1.5f * d)) & 63;
        int xs2 = ((int)(3.0f * d)) & 63;
        float wgt = fsig(s_rw[i]) * decay * 3.0f;

        conv_mlp(bufB, y, x0, ys, xs, wgt, fe, wvs4, s_d1w4, s_d1b2, s_d2p, fbv, acc);

        // intermediate snapshot (after 0.24 update) -> bufA
        #pragma unroll
        for (int p = 0; p < 4; ++p)
            bufA[wbase | (p << 4)] = make_float4(fbv[p][0], fbv[p][1], fbv[p][2], fbv[p][3]);
        __syncthreads();

        // prev = roll(fb_inter) * fades, fb += 0.08*prev
        {
            int rb2 = ((y - ys2) & 63) << 6;
            float fy2 = fe[y + 1];
            #pragma unroll
            for (int p = 0; p < 4; ++p) {
                int xp = x0 + p;
                float4 v = bufA[rb2 + permc((xp - xs2) & 63)];
                float f = 0.08f * fy2 * fe[xp + 1];
                fbv[p][0] = fmaf(v.x, f, fbv[p][0]);
                fbv[p][1] = fmaf(v.y, f, fbv[p][1]);
                fbv[p][2] = fmaf(v.z, f, fbv[p][2]);
                fbv[p][3] = fmaf(v.w, f, fbv[p][3]);
            }
        }
        // final snapshot -> bufB (safe: all conv reads of bufB passed mid-sync)
        #pragma unroll
        for (int p = 0; p < 4; ++p)
            bufB[wbase | (p << 4)] = make_float4(fbv[p][0], fbv[p][1], fbv[p][2], fbv[p][3]);
        __syncthreads();
        decay *= 0.8f;
    }

    #pragma unroll
    for (int p = 0; p < 4; ++p) {
        int s = (y << 6) + x0 + p;
        ((float4*)ws_wet)[(b << 12) + s] =
            make_float4(acc[p][0], acc[p][1], acc[p][2], acc[p][3]);
    }
}

// ---------------------------------------------------------------------------
// Kernel 2: attention (head_dim=1). Grid: 4b x 4h x 32 q-chunks = 512 blocks,
// 512 threads: 128 rows x 4 key-quarters. 2 blocks/CU.
// ---------------------------------------------------------------------------
__global__ __launch_bounds__(512) void attn_kernel(
    const float4* __restrict__ wet, const float* __restrict__ aiw,
    const float* __restrict__ aib, float* __restrict__ o_out)
{
    __shared__ float4 kvs4[2048];        // (k,v) pairs for 4096 positions
    __shared__ float redmx[8], redmn[8];
    __shared__ float2 part[512];

    const int tid = threadIdx.x;
    const int bid = blockIdx.x;
    const int b  = bid >> 7;
    const int h  = (bid >> 5) & 3;
    const int qc = bid & 31;

    float wq[4], wk[4], wv[4];
    #pragma unroll
    for (int c = 0; c < 4; ++c) {
        wq[c] = aiw[h * 4 + c];
        wk[c] = aiw[(4 + h) * 4 + c];
        wv[c] = aiw[(8 + h) * 4 + c];
    }
    const float bq = aib[h], bk = aib[4 + h], bv = aib[8 + h];

    float2* kvs = (float2*)kvs4;
    float lmax = -1e30f, lmin = 1e30f;
    for (int s = tid; s < 4096; s += 512) {
        float4 w4 = wet[(b << 12) + s];
        float k = wk[0] * w4.x + wk[1] * w4.y + wk[2] * w4.z + wk[3] * w4.w + bk;
        float v = wv[0] * w4.x + wv[1] * w4.y + wv[2] * w4.z + wv[3] * w4.w + bv;
        kvs[s] = make_float2(k, v);
        lmax = fmaxf(lmax, k); lmin = fminf(lmin, k);
    }
    #pragma unroll
    for (int off = 32; off > 0; off >>= 1) {
        lmax = fmaxf(lmax, __shfl_xor(lmax, off));
        lmin = fminf(lmin, __shfl_xor(lmin, off));
    }
    if ((tid & 63) == 0) { redmx[tid >> 6] = lmax; redmn[tid >> 6] = lmin; }
    __syncthreads();
    float kmax = redmx[0], kmin = redmn[0];
    #pragma unroll
    for (int w = 1; w < 8; ++w) { kmax = fmaxf(kmax, redmx[w]); kmin = fminf(kmin, redmn[w]); }

    const int rloc = tid & 127;
    const int quarter = tid >> 7;
    const int row = qc * 128 + rloc;
    float4 w4 = wet[(b << 12) + row];
    float q = wq[0] * w4.x + wq[1] * w4.y + wq[2] * w4.z + wq[3] * w4.w + bq;
    float m = (q >= 0.0f) ? q * kmax : q * kmin;   // exact row max (hd=1)
    float qL = q * LOG2E, mL = m * LOG2E;

    float den0 = 0.0f, den1 = 0.0f, num0 = 0.0f, num1 = 0.0f;
    int j0 = quarter * 512;
    #pragma unroll 2
    for (int j = j0; j < j0 + 512; j += 2) {
        float4 t0 = kvs4[j], t1 = kvs4[j + 1];
        float e0 = exp2f(fmaf(qL, t0.x, -mL));
        float e1 = exp2f(fmaf(qL, t0.z, -mL));
        float e2 = exp2f(fmaf(qL, t1.x, -mL));
        float e3 = exp2f(fmaf(qL, t1.z, -mL));
        den0 += e0 + e1; den1 += e2 + e3;
        num0 = fmaf(e0, t0.y, fmaf(e1, t0.w, num0));
        num1 = fmaf(e2, t1.y, fmaf(e3, t1.w, num1));
    }
    part[tid] = make_float2(den0 + den1, num0 + num1);
    __syncthreads();
    if (quarter == 0) {
        float den = part[tid].x + part[tid + 128].x + part[tid + 256].x + part[tid + 384].x;
        float num = part[tid].y + part[tid + 128].y + part[tid + 256].y + part[tid + 384].y;
        o_out[((b << 12) + row) * 4 + h] = num * __builtin_amdgcn_rcpf(den);
    }
}

// ---------------------------------------------------------------------------
// Kernel 3: fused attn output projection + depthwise 3x3 box blur.
// ---------------------------------------------------------------------------
__global__ __launch_bounds__(256) void projblur_kernel(
    const float4* __restrict__ o_in, const float* __restrict__ aow,
    const float* __restrict__ aob, float* __restrict__ blur)
{
    __shared__ float wetL[4096];
    const int tid = threadIdx.x;
    const int bc = blockIdx.x;          // b*4 + c
    const int b = bc >> 2, c = bc & 3;
    const float w0 = aow[c * 4], w1 = aow[c * 4 + 1], w2 = aow[c * 4 + 2], w3 = aow[c * 4 + 3];
    const float bb = aob[c];
    for (int s = tid; s < 4096; s += 256) {
        float4 o = o_in[(b << 12) + s];
        wetL[s] = w0 * o.x + w1 * o.y + w2 * o.z + w3 * o.w + bb;
    }
    __syncthreads();
    for (int s = tid; s < 4096; s += 256) {
        int y = s >> 6, x = s & 63;
        float acc = 0.0f;
        for (int dy = -1; dy <= 1; ++dy) {
            int yy = y + dy; if (yy < 0 || yy > 63) continue;
            for (int dx = -1; dx <= 1; ++dx) {
                int xx = x + dx; if (xx < 0 || xx > 63) continue;
                acc += wetL[yy * 64 + xx];
            }
        }
        blur[(bc << 12) + s] = acc * (1.0f / 9.0f);
    }
}

// ---------------------------------------------------------------------------
// Kernel 4: edge enhance + spatial conv + 1x1 combine + dry/wet mix
// ---------------------------------------------------------------------------
__global__ __launch_bounds__(256) void final_kernel(
    const float* __restrict__ x, const float* __restrict__ sw, const float* __restrict__ sb,
    const float* __restrict__ ow, const float* __restrict__ ob,
    const float* __restrict__ blur, float* __restrict__ out)
{
    __shared__ float s_sw[288], s_ow[48], s_sb[8], s_ob[4];
    int tid = threadIdx.x;
    for (int j = tid; j < 288; j += 256) s_sw[j] = sw[j];
    if (tid < 48) s_ow[tid] = ow[tid];
    if (tid < 8) s_sb[tid] = sb[tid];
    if (tid < 4) s_ob[tid] = ob[tid];
    __syncthreads();

    int t = blockIdx.x * 256 + tid;   // 16384
    int b = t >> 12, s = t & 4095;
    int y = s >> 6, xx0 = s & 63;

    float spat[8];
    #pragma unroll
    for (int co = 0; co < 8; ++co) spat[co] = s_sb[co];
    for (int dy = -1; dy <= 1; ++dy) {
        int yy = y + dy;
        if (yy < 0 || yy > 63) continue;
        for (int dx = -1; dx <= 1; ++dx) {
            int xc = xx0 + dx;
            if (xc < 0 || xc > 63) continue;
            int ky = dy + 1, kx = dx + 1;
            #pragma unroll
            for (int ci = 0; ci < 4; ++ci) {
                float xv = x[((b * 4 + ci) << 12) + yy * 64 + xc];
                #pragma unroll
                for (int co = 0; co < 8; ++co)
                    spat[co] += s_sw[((co * 4 + ci) * 3 + ky) * 3 + kx] * xv;
            }
        }
    }

    float wetF[4];
    #pragma unroll
    for (int c = 0; c < 4; ++c) {
        const float* pl = blur + ((b * 4 + c) << 12);
        float center = pl[s];
        float sum9 = 0.0f;
        for (int dy = -1; dy <= 1; ++dy) {
            int yy = y + dy;
            if (yy < 0 || yy > 63) continue;
            for (int dx = -1; dx <= 1; ++dx) {
                int xc = xx0 + dx;
                if (xc < 0 || xc > 63) continue;
                sum9 += pl[yy * 64 + xc];
            }
        }
        float edge = 9.0f * center - sum9;
        wetF[c] = center + 0.04f * edge;
    }

    #pragma unroll
    for (int co = 0; co < 4; ++co) {
        float p = s_ob[co];
        #pragma unroll
        for (int j = 0; j < 8; ++j) p += s_ow[co * 12 + j] * spat[j];
        #pragma unroll
        for (int c = 0; c < 4; ++c) p += s_ow[co * 12 + 8 + c] * wetF[c];
        float xc = x[((b * 4 + co) << 12) + s];
        out[((b * 4 + co) << 12) + s] = 0.7f * xc + 0.3f * p;
    }
}

// ---------------------------------------------------------------------------
extern "C" void kernel_launch(void* const* d_in, const int* in_sizes, int n_in,
                              void* d_out, int out_size, void* d_ws, size_t ws_size,
                              hipStream_t stream)
{
    (void)in_sizes; (void)n_in; (void)out_size; (void)ws_size;
    const float* x    = (const float*)d_in[0];
    const float* rw   = (const float*)d_in[1];
    const float* dl   = (const float*)d_in[2];
    // d_in[3] diffusion_strength: unused by reference
    const float* sw   = (const float*)d_in[4];
    const float* sb   = (const float*)d_in[5];
    const float* fbw  = (const float*)d_in[6];
    const float* fbb  = (const float*)d_in[7];
    const float* d1w  = (const float*)d_in[8];
    const float* d1b  = (const float*)d_in[9];
    const float* d2w  = (const float*)d_in[10];
    const float* d2b  = (const float*)d_in[11];
    const float* aiw  = (const float*)d_in[12];
    const float* aib  = (const float*)d_in[13];
    const float* aow  = (const float*)d_in[14];
    const float* aob  = (const float*)d_in[15];
    const float* ow   = (const float*)d_in[16];
    const float* ob   = (const float*)d_in[17];
    float* out = (float*)d_out;

    float* ws_wet  = (float*)d_ws;           // [4][4096][4]
    float* ws_o    = ws_wet + 65536;         // [4][4096][4]
    float* ws_blur = ws_o + 65536;           // [4][4][4096]

    reverb_kernel<<<4, 1024, 0, stream>>>(x, rw, dl, fbw, fbb, d1w, d1b, d2w, d2b, ws_wet);
    attn_kernel<<<512, 512, 0, stream>>>((const float4*)ws_wet, aiw, aib, ws_o);
    projblur_kernel<<<16, 256, 0, stream>>>((const float4*)ws_o, aow, aob, ws_blur);
    final_kernel<<<64, 256, 0, stream>>>(x, sw, sb, ow, ob, ws_blur, out);
}

// Round 5
// 263.000 us; speedup vs baseline: 1.8008x; 1.1476x over previous
//
#include <hip/hip_runtime.h>

#define LOG2E 1.4426950408889634f
#define RNB 32   // reverb grid blocks (8 per batch); must all be co-resident (32 <= 256 CUs)

// fast sigmoid: rcp approx ~1e-6 rel; tolerance headroom is ~250x
__device__ __forceinline__ float fsig(float z) {
    return __builtin_amdgcn_rcpf(1.0f + exp2f(-z * LOG2E));
}

// ---------------------------------------------------------------------------
// Device-scope grid barrier, one-shot counter per slot (no sense reversal).
// __syncthreads drains every wave's stores to L2 (s_waitcnt vmcnt(0) before
// s_barrier); tid0's __threadfence does the agent-scope L2 writeback; reader
// side fence invalidates caches.  Counters are 64B-spaced.
// ---------------------------------------------------------------------------
__device__ __forceinline__ void grid_bar(unsigned* cnt, int slot) {
    __syncthreads();
    if (threadIdx.x == 0) {
        __threadfence();
        atomicAdd(&cnt[slot * 16], 1u);
        while (atomicAdd(&cnt[slot * 16], 0u) < (unsigned)RNB)
            __builtin_amdgcn_s_sleep(2);
        __threadfence();
    }
    __syncthreads();
}

__global__ __launch_bounds__(256) void bar_init(unsigned* cnt) {
    cnt[threadIdx.x] = 0u;   // 256 uints = 16 slots x 64B
}

// ---------------------------------------------------------------------------
// conv3x3(roll(fb)*fade) + damping MLP at one pixel, fb in global memory.
// Weights live in VGPRs (wr), fades in LDS (broadcast/stride-1 reads).
// ---------------------------------------------------------------------------
__device__ __forceinline__ void conv_damp(
    const float4* __restrict__ src, int yq, int xq, int ys, int xs,
    const float* fe, const float4 wr[9][4],
    const float4 d1w0, const float4 d1w1, const float2 d1b, const float4 d2p[4],
    float rv[4])
{
    float r[4] = { d2p[0].w, d2p[1].w, d2p[2].w, d2p[3].w };   // conv bias (fbb)
    #pragma unroll
    for (int a = 0; a < 3; ++a) {
        int yy = yq - 1 + a;
        float fy = fe[yy + 1];                       // 0 outside image -> zero pad
        const float4* rowp = src + (((yy - ys) & 63) << 6);
        #pragma unroll
        for (int qq = 0; qq < 3; ++qq) {
            int xt = xq - 1 + qq;
            float f = fy * fe[xt + 1];
            float4 v = rowp[(xt - xs) & 63];
            float s0 = v.x * f, s1 = v.y * f, s2 = v.z * f, s3 = v.w * f;
            #pragma unroll
            for (int co = 0; co < 4; ++co) {
                float4 w = wr[a * 3 + qq][co];
                r[co] = fmaf(w.x, s0, fmaf(w.y, s1, fmaf(w.z, s2, fmaf(w.w, s3, r[co]))));
            }
        }
    }
    float z0 = fmaf(d1w0.x, r[0], fmaf(d1w0.y, r[1], fmaf(d1w0.z, r[2], fmaf(d1w0.w, r[3], d1b.x))));
    float z1 = fmaf(d1w1.x, r[0], fmaf(d1w1.y, r[1], fmaf(d1w1.z, r[2], fmaf(d1w1.w, r[3], d1b.y))));
    float h0 = z0 * fsig(z0);
    float h1 = z1 * fsig(z1);
    #pragma unroll
    for (int c = 0; c < 4; ++c) {
        float dm = fsig(fmaf(d2p[c].x, h0, fmaf(d2p[c].y, h1, d2p[c].z)));
        rv[c] = r[c] * dm;
    }
}

// ---------------------------------------------------------------------------
// Kernel 1: multi-block reverb. 32 blocks x 512 threads; block owns 8 rows of
// one batch, 1 px/thread. fb double-buffered in global (A even-i src, B odd).
// One grid barrier per iteration: phase2's remote fbI is recomputed locally.
// ---------------------------------------------------------------------------
__global__ __launch_bounds__(512) void reverb_mb(
    const float* __restrict__ x, const float* __restrict__ rw, const float* __restrict__ dl,
    const float* __restrict__ fbw, const float* __restrict__ fbb,
    const float* __restrict__ d1wg, const float* __restrict__ d1bg,
    const float* __restrict__ d2wg, const float* __restrict__ d2bg,
    float4* __restrict__ fbA, float4* __restrict__ fbB,
    unsigned* __restrict__ cnt, float4* __restrict__ ws_wet)
{
    __shared__ float fe[66];          // fade, zero pad at 0 and 65
    __shared__ float4 wvsL[36];       // [tap][cout] -> cin quad
    __shared__ float s_rw[16], s_dl[16];
    __shared__ float4 s_mlp[7];       // [0..1]=d1w rows, [2].xy=d1b, [3..6]=(d2w0,d2w1,d2b,fbb)

    const int tid = threadIdx.x;
    const int b   = blockIdx.x >> 3;
    const int blk = blockIdx.x & 7;

    if (tid < 66) {
        float f = 0.0f;
        if (tid >= 1 && tid <= 64) {
            int j = tid - 1;
            f = 1.0f;
            if (j < 4) f = 0.6f + (0.4f / 3.0f) * j;
            else if (j >= 60) f = 0.6f + (0.4f / 3.0f) * (63 - j);
        }
        fe[tid] = f;
    }
    if (tid >= 128 && tid < 164) {
        int t2 = tid - 128, n = t2 >> 2, co = t2 & 3;
        wvsL[t2] = make_float4(fbw[(co * 4 + 0) * 9 + n], fbw[(co * 4 + 1) * 9 + n],
                               fbw[(co * 4 + 2) * 9 + n], fbw[(co * 4 + 3) * 9 + n]);
    }
    if (tid >= 192 && tid < 208) s_rw[tid - 192] = rw[tid - 192];
    if (tid >= 256 && tid < 272) s_dl[tid - 256] = dl[tid - 256];
    if (tid == 320) {
        s_mlp[0] = make_float4(d1wg[0], d1wg[1], d1wg[2], d1wg[3]);
        s_mlp[1] = make_float4(d1wg[4], d1wg[5], d1wg[6], d1wg[7]);
        s_mlp[2] = make_float4(d1bg[0], d1bg[1], 0.0f, 0.0f);
        for (int c = 0; c < 4; ++c)
            s_mlp[3 + c] = make_float4(d2wg[c * 2], d2wg[c * 2 + 1], d2bg[c], fbb[c]);
    }

    const int ly = tid >> 6;              // 0..7
    const int y0 = (blk << 3) + ly;
    const int xx = tid & 63;
    float4* A = fbA + (b << 12);
    float4* B = fbB + (b << 12);

    float4 fbv;
    fbv.x = 0.1f * x[((b * 4 + 0) << 12) + (y0 << 6) + xx];
    fbv.y = 0.1f * x[((b * 4 + 1) << 12) + (y0 << 6) + xx];
    fbv.z = 0.1f * x[((b * 4 + 2) << 12) + (y0 << 6) + xx];
    fbv.w = 0.1f * x[((b * 4 + 3) << 12) + (y0 << 6) + xx];
    A[(y0 << 6) + xx] = fbv;
    __syncthreads();

    // LDS -> registers (re-reading LDS across barriers can't be CSE'd)
    float4 wr[9][4];
    #pragma unroll
    for (int n = 0; n < 9; ++n)
        #pragma unroll
        for (int co = 0; co < 4; ++co) wr[n][co] = wvsL[n * 4 + co];
    const float4 d1w0 = s_mlp[0], d1w1 = s_mlp[1];
    const float2 d1b = make_float2(s_mlp[2].x, s_mlp[2].y);
    float4 d2p[4] = { s_mlp[3], s_mlp[4], s_mlp[5], s_mlp[6] };

    grid_bar(cnt, 0);   // fb0 visible device-wide

    float acc0 = 0.0f, acc1 = 0.0f, acc2 = 0.0f, acc3 = 0.0f;
    float decay = 1.0f;
    for (int i = 0; i < 16; ++i) {
        const float4* src = (i & 1) ? B : A;
        float4* dst = (i & 1) ? A : B;
        float d = s_dl[i];
        int ys  = ((int)(3.0f * d)) & 63;
        int xs  = ((int)(6.0f * d)) & 63;
        int ys2 = ((int)(1.5f * d)) & 63;
        int xs2 = ((int)(3.0f * d)) & 63;
        float wgt = fsig(s_rw[i]) * decay * 3.0f;

        float rv[4];
        conv_damp(src, y0, xx, ys, xs, fe, wr, d1w0, d1w1, d1b, d2p, rv);
        acc0 = fmaf(rv[0], wgt, acc0);
        acc1 = fmaf(rv[1], wgt, acc1);
        acc2 = fmaf(rv[2], wgt, acc2);
        acc3 = fmaf(rv[3], wgt, acc3);
        float4 fnew = make_float4(fbv.x + 0.24f * rv[0], fbv.y + 0.24f * rv[1],
                                  fbv.z + 0.24f * rv[2], fbv.w + 0.24f * rv[3]);
        if (i > 0) {
            // prev = roll(fbI, d/2) * fades; fbI at remote px recomputed locally
            int yr = (y0 - ys2) & 63, xr = (xx - xs2) & 63;
            float rvr[4];
            conv_damp(src, yr, xr, ys, xs, fe, wr, d1w0, d1w1, d1b, d2p, rvr);
            float4 fr = src[(yr << 6) + xr];
            float f = 0.08f * fe[y0 + 1] * fe[xx + 1];
            fnew.x = fmaf(f, fmaf(0.24f, rvr[0], fr.x), fnew.x);
            fnew.y = fmaf(f, fmaf(0.24f, rvr[1], fr.y), fnew.y);
            fnew.z = fmaf(f, fmaf(0.24f, rvr[2], fr.z), fnew.z);
            fnew.w = fmaf(f, fmaf(0.24f, rvr[3], fr.w), fnew.w);
        }
        dst[(y0 << 6) + xx] = fnew;
        fbv = fnew;
        if (i < 15) grid_bar(cnt, i + 1);
        decay *= 0.8f;
    }

    ws_wet[(b << 12) + (y0 << 6) + xx] = make_float4(acc0, acc1, acc2, acc3);
}

// ---------------------------------------------------------------------------
// Kernel 2: attention (head_dim=1). Grid 512: b x h x 32 q-chunks of 128 rows.
// 512 threads = 32 row-slots (4 rows each) x 16 key-groups -> 4x fewer LDS
// reads per wave than 1-row/thread; now trans/VALU-bound.
// ---------------------------------------------------------------------------
__global__ __launch_bounds__(512) void attn_kernel(
    const float4* __restrict__ wet, const float* __restrict__ aiw,
    const float* __restrict__ aib, float* __restrict__ o_out)
{
    __shared__ float4 kvs4[2048];        // (k,v) pairs for 4096 positions
    __shared__ float redmx[8], redmn[8];
    __shared__ float2 part[2048];        // [kg][row_local]

    const int tid = threadIdx.x;
    const int bid = blockIdx.x;
    const int b  = bid >> 7;
    const int h  = (bid >> 5) & 3;
    const int qc = bid & 31;

    float wq[4], wk[4], wv[4];
    #pragma unroll
    for (int c = 0; c < 4; ++c) {
        wq[c] = aiw[h * 4 + c];
        wk[c] = aiw[(4 + h) * 4 + c];
        wv[c] = aiw[(8 + h) * 4 + c];
    }
    const float bq = aib[h], bk = aib[4 + h], bv = aib[8 + h];

    float2* kvs = (float2*)kvs4;
    float lmax = -1e30f, lmin = 1e30f;
    for (int s = tid; s < 4096; s += 512) {
        float4 w4 = wet[(b << 12) + s];
        float k = wk[0] * w4.x + wk[1] * w4.y + wk[2] * w4.z + wk[3] * w4.w + bk;
        float v = wv[0] * w4.x + wv[1] * w4.y + wv[2] * w4.z + wv[3] * w4.w + bv;
        kvs[s] = make_float2(k, v);
        lmax = fmaxf(lmax, k); lmin = fminf(lmin, k);
    }
    #pragma unroll
    for (int off = 32; off > 0; off >>= 1) {
        lmax = fmaxf(lmax, __shfl_xor(lmax, off));
        lmin = fminf(lmin, __shfl_xor(lmin, off));
    }
    if ((tid & 63) == 0) { redmx[tid >> 6] = lmax; redmn[tid >> 6] = lmin; }
    __syncthreads();
    float kmax = redmx[0], kmin = redmn[0];
    #pragma unroll
    for (int w = 1; w < 8; ++w) { kmax = fmaxf(kmax, redmx[w]); kmin = fminf(kmin, redmn[w]); }

    const int rs = tid & 31;
    const int kg = tid >> 5;
    float qL[4], mL[4];
    #pragma unroll
    for (int rr = 0; rr < 4; ++rr) {
        int row = (qc << 7) + (rs << 2) + rr;
        float4 w4 = wet[(b << 12) + row];
        float q = wq[0] * w4.x + wq[1] * w4.y + wq[2] * w4.z + wq[3] * w4.w + bq;
        float m = (q >= 0.0f) ? q * kmax : q * kmin;   // exact row max (hd=1)
        qL[rr] = q * LOG2E; mL[rr] = m * LOG2E;
    }

    float den[4] = {0, 0, 0, 0}, num[4] = {0, 0, 0, 0};
    const int j0 = kg << 7;
    #pragma unroll 2
    for (int j = j0; j < j0 + 128; ++j) {
        float4 t = kvs4[j];
        #pragma unroll
        for (int rr = 0; rr < 4; ++rr) {
            float e0 = exp2f(fmaf(qL[rr], t.x, -mL[rr]));
            float e1 = exp2f(fmaf(qL[rr], t.z, -mL[rr]));
            den[rr] += e0 + e1;
            num[rr] = fmaf(e0, t.y, fmaf(e1, t.w, num[rr]));
        }
    }
    #pragma unroll
    for (int rr = 0; rr < 4; ++rr)
        part[(kg << 7) + (rs << 2) + rr] = make_float2(den[rr], num[rr]);
    __syncthreads();
    if (tid < 128) {
        float dd = 0.0f, nn = 0.0f;
        #pragma unroll
        for (int g = 0; g < 16; ++g) {
            float2 p = part[(g << 7) + tid];
            dd += p.x; nn += p.y;
        }
        int row = (qc << 7) + tid;
        o_out[((b << 12) + row) * 4 + h] = nn * __builtin_amdgcn_rcpf(dd);
    }
}

// ---------------------------------------------------------------------------
// Kernel 3: fused attn output projection + depthwise 3x3 box blur.
// ---------------------------------------------------------------------------
__global__ __launch_bounds__(256) void projblur_kernel(
    const float4* __restrict__ o_in, const float* __restrict__ aow,
    const float* __restrict__ aob, float* __restrict__ blur)
{
    __shared__ float wetL[4096];
    const int tid = threadIdx.x;
    const int bc = blockIdx.x;          // b*4 + c
    const int b = bc >> 2, c = bc & 3;
    const float w0 = aow[c * 4], w1 = aow[c * 4 + 1], w2 = aow[c * 4 + 2], w3 = aow[c * 4 + 3];
    const float bb = aob[c];
    for (int s = tid; s < 4096; s += 256) {
        float4 o = o_in[(b << 12) + s];
        wetL[s] = w0 * o.x + w1 * o.y + w2 * o.z + w3 * o.w + bb;
    }
    __syncthreads();
    for (int s = tid; s < 4096; s += 256) {
        int y = s >> 6, x = s & 63;
        float acc = 0.0f;
        for (int dy = -1; dy <= 1; ++dy) {
            int yy = y + dy; if (yy < 0 || yy > 63) continue;
            for (int dx = -1; dx <= 1; ++dx) {
                int xx = x + dx; if (xx < 0 || xx > 63) continue;
                acc += wetL[yy * 64 + xx];
            }
        }
        blur[(bc << 12) + s] = acc * (1.0f / 9.0f);
    }
}

// ---------------------------------------------------------------------------
// Kernel 4: edge enhance + spatial conv + 1x1 combine + dry/wet mix
// ---------------------------------------------------------------------------
__global__ __launch_bounds__(256) void final_kernel(
    const float* __restrict__ x, const float* __restrict__ sw, const float* __restrict__ sb,
    const float* __restrict__ ow, const float* __restrict__ ob,
    const float* __restrict__ blur, float* __restrict__ out)
{
    __shared__ float s_sw[288], s_ow[48], s_sb[8], s_ob[4];
    int tid = threadIdx.x;
    for (int j = tid; j < 288; j += 256) s_sw[j] = sw[j];
    if (tid < 48) s_ow[tid] = ow[tid];
    if (tid < 8) s_sb[tid] = sb[tid];
    if (tid < 4) s_ob[tid] = ob[tid];
    __syncthreads();

    int t = blockIdx.x * 256 + tid;   // 16384
    int b = t >> 12, s = t & 4095;
    int y = s >> 6, xx0 = s & 63;

    float spat[8];
    #pragma unroll
    for (int co = 0; co < 8; ++co) spat[co] = s_sb[co];
    for (int dy = -1; dy <= 1; ++dy) {
        int yy = y + dy;
        if (yy < 0 || yy > 63) continue;
        for (int dx = -1; dx <= 1; ++dx) {
            int xc = xx0 + dx;
            if (xc < 0 || xc > 63) continue;
            int ky = dy + 1, kx = dx + 1;
            #pragma unroll
            for (int ci = 0; ci < 4; ++ci) {
                float xv = x[((b * 4 + ci) << 12) + yy * 64 + xc];
                #pragma unroll
                for (int co = 0; co < 8; ++co)
                    spat[co] += s_sw[((co * 4 + ci) * 3 + ky) * 3 + kx] * xv;
            }
        }
    }

    float wetF[4];
    #pragma unroll
    for (int c = 0; c < 4; ++c) {
        const float* pl = blur + ((b * 4 + c) << 12);
        float center = pl[s];
        float sum9 = 0.0f;
        for (int dy = -1; dy <= 1; ++dy) {
            int yy = y + dy;
            if (yy < 0 || yy > 63) continue;
            for (int dx = -1; dx <= 1; ++dx) {
                int xc = xx0 + dx;
                if (xc < 0 || xc > 63) continue;
                sum9 += pl[yy * 64 + xc];
            }
        }
        float edge = 9.0f * center - sum9;
        wetF[c] = center + 0.04f * edge;
    }

    #pragma unroll
    for (int co = 0; co < 4; ++co) {
        float p = s_ob[co];
        #pragma unroll
        for (int j = 0; j < 8; ++j) p += s_ow[co * 12 + j] * spat[j];
        #pragma unroll
        for (int c = 0; c < 4; ++c) p += s_ow[co * 12 + 8 + c] * wetF[c];
        float xc = x[((b * 4 + co) << 12) + s];
        out[((b * 4 + co) << 12) + s] = 0.7f * xc + 0.3f * p;
    }
}

// ---------------------------------------------------------------------------
extern "C" void kernel_launch(void* const* d_in, const int* in_sizes, int n_in,
                              void* d_out, int out_size, void* d_ws, size_t ws_size,
                              hipStream_t stream)
{
    (void)in_sizes; (void)n_in; (void)out_size; (void)ws_size;
    const float* x    = (const float*)d_in[0];
    const float* rw   = (const float*)d_in[1];
    const float* dl   = (const float*)d_in[2];
    // d_in[3] diffusion_strength: unused by reference
    const float* sw   = (const float*)d_in[4];
    const float* sb   = (const float*)d_in[5];
    const float* fbw  = (const float*)d_in[6];
    const float* fbb  = (const float*)d_in[7];
    const float* d1w  = (const float*)d_in[8];
    const float* d1b  = (const float*)d_in[9];
    const float* d2w  = (const float*)d_in[10];
    const float* d2b  = (const float*)d_in[11];
    const float* aiw  = (const float*)d_in[12];
    const float* aib  = (const float*)d_in[13];
    const float* aow  = (const float*)d_in[14];
    const float* aob  = (const float*)d_in[15];
    const float* ow   = (const float*)d_in[16];
    const float* ob   = (const float*)d_in[17];
    float* out = (float*)d_out;

    // ws layout (<= 786432 B proven available):
    float* ws_wet  = (float*)d_ws;                   // [4][4096] float4  (256 KB)
    float* fbA     = ws_wet + 65536;                 // [4][4096] float4  (256 KB); reused as ws_o
    float* fbB     = fbA + 65536;                    // [4][4096] float4  (256 KB); reused as ws_blur
    unsigned* cnt  = (unsigned*)(fbB + 65536);       // 1 KB barrier counters
    float* ws_o    = fbA;
    float* ws_blur = fbB;

    bar_init<<<1, 256, 0, stream>>>(cnt);
    reverb_mb<<<RNB, 512, 0, stream>>>(x, rw, dl, fbw, fbb, d1w, d1b, d2w, d2b,
                                       (float4*)fbA, (float4*)fbB, cnt, (float4*)ws_wet);
    attn_kernel<<<512, 512, 0, stream>>>((const float4*)ws_wet, aiw, aib, ws_o);
    projblur_kernel<<<16, 256, 0, stream>>>((const float4*)ws_o, aow, aob, ws_blur);
    final_kernel<<<64, 256, 0, stream>>>(x, sw, sb, ow, ob, ws_blur, out);
}